// Round 7
// baseline (680.262 us; speedup 1.0000x reference)
//
#include <hip/hip_runtime.h>
#include <hip/hip_fp16.h>
#include <math.h>

#define CCH  384
#define BATCH 8
#define HWN  4096
#define NG   32
#define CPG  12
#define KSEL 512
#define FFTP 65   // FFT LDS pitch
#define LP   40   // mm LDS pitch (bf16 units)

typedef short v8s  __attribute__((ext_vector_type(8)));   // 8 bf16 (4 VGPRs)
typedef float v16f __attribute__((ext_vector_type(16)));  // 32x32 acc

#define MFMA_B16(A_,B_,C_) __builtin_amdgcn_mfma_f32_32x32x16_bf16((A_),(B_),(C_),0,0,0)

// barrier WITHOUT the vmcnt(0) drain __syncthreads would emit: ds_writes are
// published (lgkmcnt(0)) but global-load prefetches stay in flight across the
// barrier; consumers wait on their own data via compiler-inserted vmcnt(N).
#define BARRIER_NODRAIN() asm volatile("s_waitcnt lgkmcnt(0)\n\ts_barrier" ::: "memory")
// raw barrier: nothing drained (ds_reads already consumed by MFMAs).
#define BARRIER_RAW() asm volatile("s_barrier" ::: "memory")

__device__ __forceinline__ v8s as_v8s(uint4 u) {
  union { uint4 u4; v8s v; } c; c.u4 = u; return c.v;
}
__device__ __forceinline__ unsigned br6(unsigned i) {
  return ((i&1u)<<5)|((i&2u)<<3)|((i&4u)<<1)|((i&8u)>>1)|((i&16u)>>3)|((i&32u)>>5);
}
__device__ __forceinline__ unsigned f2key(float f) {
  unsigned u = __float_as_uint(f);
  return (u & 0x80000000u) ? ~u : (u | 0x80000000u);
}
__device__ __forceinline__ float wave_max(float v) {
#pragma unroll
  for (int o = 32; o > 0; o >>= 1) v = fmaxf(v, __shfl_down(v, o, 64));
  return v;
}
__device__ __forceinline__ float wave_sum(float v) {
#pragma unroll
  for (int o = 32; o > 0; o >>= 1) v += __shfl_down(v, o, 64);
  return v;
}
__device__ __forceinline__ unsigned short bf16_rne(float f) {
  unsigned u = __float_as_uint(f);
  return (unsigned short)((u + 0x7fffu + ((u >> 16) & 1u)) >> 16);
}
__device__ __forceinline__ float bf2f(unsigned short h) {
  return __uint_as_float(((unsigned)h) << 16);
}

// ---------------- group stats (mu, rsqrt(var+eps)) per (b,g) ----------------
__global__ __launch_bounds__(256) void stats_kernel(const float* __restrict__ x,
                                                    float2* __restrict__ gs,
                                                    unsigned short* __restrict__ zp) {
  int b = blockIdx.x >> 5, g = blockIdx.x & 31;
  if (blockIdx.x == 0 && threadIdx.x < 8) zp[threadIdx.x] = 0;  // zero page
  size_t base = ((size_t)b * CCH + (size_t)g * CPG) * HWN;
  const float4* xp = (const float4*)(x + base);
  int tid = threadIdx.x;
  const int N4 = CPG * HWN / 4;
  float s = 0.f, ss = 0.f;
  for (int i = tid; i < N4; i += 256) {
    float4 v = xp[i];
    s  += (v.x + v.y) + (v.z + v.w);
    ss += (v.x*v.x + v.y*v.y) + (v.z*v.z + v.w*v.w);
  }
  s = wave_sum(s); ss = wave_sum(ss);
  __shared__ float sb[4], qb[4];
  if ((tid & 63) == 0) { sb[tid >> 6] = s; qb[tid >> 6] = ss; }
  __syncthreads();
  if (tid == 0) {
    float S = sb[0]+sb[1]+sb[2]+sb[3], Q = qb[0]+qb[1]+qb[2]+qb[3];
    float inv = 1.0f / (float)(CPG * HWN);
    float mu = S * inv;
    float var = Q * inv - mu * mu;
    gs[blockIdx.x] = make_float2(mu, rsqrtf(var + 1e-5f));
  }
}

// ------- weight pack: fp32 -> bf16 hi + lo, in MFMA A-fragment order --------
// frag layout: frag_id = (r*24 + kc)*12 + mb   (kc = K/16 chunk, mb = M/32)
// within frag: lane l (0..63) holds A[mb*32 + (l&31)][kc*16 + (l>>5)*8 + j]
__global__ __launch_bounds__(256) void pack_split_k(const float* __restrict__ w,
    unsigned short* __restrict__ hi, unsigned short* __restrict__ lo, int n) {
  int i = blockIdx.x * 256 + threadIdx.x;
  if (i >= n) return;
  float f = w[i];
  int m = i / 384, ci = i - m * 384;
  int kc = ci >> 4, tt = ci & 15;
  int mb = m >> 5, lm2 = m & 31;
  int l = ((tt >> 3) << 5) | lm2;
  int j = tt & 7;
  size_t o = (((size_t)kc * 12 + mb) << 9) + ((size_t)l << 3) + j;
  unsigned short h = bf16_rne(f);
  hi[o] = h;
  lo[o] = bf16_rne(f - bf2f(h));
}
// wk[m][ci][r] (r=3x3 tap) -> fragment-packed planes per r
__global__ __launch_bounds__(256) void pack9_k(const float* __restrict__ w,
    unsigned short* __restrict__ hi, unsigned short* __restrict__ lo) {
  int i = blockIdx.x * 256 + threadIdx.x;     // 0..147455 == m*384+ci
  int r = blockIdx.y;
  float f = w[(size_t)i * 9 + r];
  int m = i / 384, ci = i - m * 384;
  int kc = ci >> 4, tt = ci & 15;
  int mb = m >> 5, lm2 = m & 31;
  int l = ((tt >> 3) << 5) | lm2;
  int j = tt & 7;
  size_t o = (((size_t)(r * 24 + kc) * 12 + mb) << 9) + ((size_t)l << 3) + j;
  unsigned short h = bf16_rne(f);
  hi[o] = h;
  lo[o] = bf16_rne(f - bf2f(h));
}

// ---- transpose NCHW fp32 -> NHWC bf16 hi(/lo); FUSE=1 applies GroupNorm ----
template<int FUSE, int SPLIT>
__global__ __launch_bounds__(256) void trans_kernel(const float* __restrict__ in,
    const float2* __restrict__ gs, const float* __restrict__ gamma,
    const float* __restrict__ beta,
    unsigned short* __restrict__ oh, unsigned short* __restrict__ ol) {
  __shared__ float ts[64][65];
  int tid = threadIdx.x;
  int b = blockIdx.z, c0 = blockIdx.y * 64, p0 = blockIdx.x * 64;
#pragma unroll
  for (int i = 0; i < 4; ++i) {
    int idx = tid + (i << 8);
    int row = idx >> 4, col = (idx & 15) << 2;
    float4 v = *(const float4*)&in[((size_t)b*CCH + c0 + row)*HWN + p0 + col];
    if (FUSE) {
      int c = c0 + row;
      float2 st = gs[(b << 5) + c / CPG];
      float a = gamma[c] * st.y, bb = beta[c] - st.x * a;
      v.x = v.x*a+bb; v.y = v.y*a+bb; v.z = v.z*a+bb; v.w = v.w*a+bb;
    }
    ts[row][col] = v.x; ts[row][col+1] = v.y; ts[row][col+2] = v.z; ts[row][col+3] = v.w;
  }
  __syncthreads();
#pragma unroll
  for (int i = 0; i < 2; ++i) {
    int idx = tid + (i << 8);
    int p = idx >> 3, cgp = (idx & 7) << 3;
    unsigned short h8[8] __attribute__((aligned(16)));
    unsigned short l8[8] __attribute__((aligned(16)));
#pragma unroll
    for (int j = 0; j < 8; ++j) {
      float f = ts[cgp + j][p];
      unsigned short hb = bf16_rne(f);
      h8[j] = hb;
      if (SPLIT) l8[j] = bf16_rne(f - bf2f(hb));
    }
    size_t o = ((size_t)b*HWN + p0 + p)*CCH + c0 + cgp;
    *(uint4*)&oh[o] = *(const uint4*)h8;
    if (SPLIT) *(uint4*)&ol[o] = *(const uint4*)l8;
  }
}

// ------------- MFMA GEMM (1x1 convs), bf16 2-term split -----------------
// BN=64 (one image row per block): grid (64,3,8) = 1536 blocks = 6/CU, the
// TLP needed to overlap the per-wave ds_read->MFMA dependency chain across
// blocks.  Per-wave structure identical to the proven R5 form, n-extent
// halved: acc[2] (one 32-wide n-tile per wave), B buffers 64 rows.
// OUT: 0 = fp32 NCHW, 1 = fp16 NCHW, 2 = fp32 NCHW * (xnT_h+xnT_l) -> d_out
template<int TAPS, int OUT>
__global__ __launch_bounds__(256, 4) void mm_kernel(
    const unsigned short* __restrict__ Ahg, const unsigned short* __restrict__ Alg,
    const float* __restrict__ bias,
    const unsigned short* __restrict__ Bhg, const unsigned short* __restrict__ Blg,
    const unsigned short* __restrict__ xnTh, const unsigned short* __restrict__ xnTl,
    void* __restrict__ Yv) {
  __shared__ unsigned short Bh_s[2][64*LP], Bl_s[2][64*LP];   // 20.5 KB
  int tid = threadIdx.x;
  int b = blockIdx.z, m0 = blockIdx.y * 128;
  int n0 = blockIdx.x << 6;                // pixel base = image row * 64
  int u0row = tid >> 2, cg = tid & 3;      // staging atom: 16B = 8 bf16
  int lds0 = u0row * LP + cg * 8;
  int lane = tid & 63, wm = tid >> 7, wn = (tid >> 6) & 1;
  int lm = lane & 31, lh = lane >> 5;
  int brow = (wn * 32 + lm) * LP;
  int mbb = blockIdx.y * 4 + wm * 2;       // M/32 block base for this wave
  int laneoff = lane << 3;

  v16f acc[2];
#pragma unroll
  for (int t = 0; t < 2; ++t)
#pragma unroll
    for (int g = 0; g < 16; ++g) acc[t][g] = 0.f;

  const int NS = 12;
  uint4 rbh, rbl;
  uint4 rA0h_h0, rA0l_h0, rA1h_h0, rA1l_h0;   // step-current A frags, h=0
  uint4 rA0h_h1, rA0l_h1, rA1h_h1, rA1l_h1;   // step-current A frags, h=1

  auto issueB = [&](int s) {
    size_t boff = ((size_t)b * HWN + n0 + u0row) * CCH + cg * 8 + s * 32;
    rbh = *(const uint4*)(Bhg + boff);
    rbl = *(const uint4*)(Blg + boff);
  };
  auto loadA0 = [&](int s) {                 // fragments for half-step h=0
    int fragcol = s * 2;
    size_t off = (((size_t)fragcol * 12 + mbb) << 9) + laneoff;
    rA0h_h0 = *(const uint4*)(Ahg + off);
    rA0l_h0 = *(const uint4*)(Alg + off);
    rA1h_h0 = *(const uint4*)(Ahg + off + 512);
    rA1l_h0 = *(const uint4*)(Alg + off + 512);
  };
  auto loadA1 = [&](int s) {                 // fragments for half-step h=1
    int fragcol = s * 2 + 1;
    size_t off = (((size_t)fragcol * 12 + mbb) << 9) + laneoff;
    rA0h_h1 = *(const uint4*)(Ahg + off);
    rA0l_h1 = *(const uint4*)(Alg + off);
    rA1h_h1 = *(const uint4*)(Ahg + off + 512);
    rA1l_h1 = *(const uint4*)(Alg + off + 512);
  };

  // prologue: B(0) -> buf0, A(0) -> regs, B(1) -> regs
  issueB(0);
  loadA0(0); loadA1(0);
  *(uint4*)&Bh_s[0][lds0] = rbh; *(uint4*)&Bl_s[0][lds0] = rbl;
  issueB(1);
  BARRIER_NODRAIN();

  for (int s = 0; s < NS; ++s) {
    const int cur = s & 1;
    const unsigned short* Bh = &Bh_s[cur][0];
    const unsigned short* Bl = &Bl_s[cur][0];
    {
      int co = lh << 3;
      v8s b0h = *(const v8s*)&Bh[brow + co];
      v8s b0l = *(const v8s*)&Bl[brow + co];
      v8s a0h = as_v8s(rA0h_h0), a0l = as_v8s(rA0l_h0);
      v8s a1h = as_v8s(rA1h_h0), a1l = as_v8s(rA1l_h0);
      __builtin_amdgcn_s_setprio(1);
      acc[0] = MFMA_B16(a0h, b0h, acc[0]);
      acc[0] = MFMA_B16(a0h, b0l, acc[0]);
      acc[0] = MFMA_B16(a0l, b0h, acc[0]);
      acc[1] = MFMA_B16(a1h, b0h, acc[1]);
      acc[1] = MFMA_B16(a1h, b0l, acc[1]);
      acc[1] = MFMA_B16(a1l, b0h, acc[1]);
      __builtin_amdgcn_s_setprio(0);
    }
    if (s + 1 < NS) loadA0(s + 1);   // latency hides under h=1 MFMAs
    {
      int co = 16 + (lh << 3);
      v8s b0h = *(const v8s*)&Bh[brow + co];
      v8s b0l = *(const v8s*)&Bl[brow + co];
      v8s a0h = as_v8s(rA0h_h1), a0l = as_v8s(rA0l_h1);
      v8s a1h = as_v8s(rA1h_h1), a1l = as_v8s(rA1l_h1);
      __builtin_amdgcn_s_setprio(1);
      acc[0] = MFMA_B16(a0h, b0h, acc[0]);
      acc[0] = MFMA_B16(a0h, b0l, acc[0]);
      acc[0] = MFMA_B16(a0l, b0h, acc[0]);
      acc[1] = MFMA_B16(a1h, b0h, acc[1]);
      acc[1] = MFMA_B16(a1h, b0l, acc[1]);
      acc[1] = MFMA_B16(a1l, b0h, acc[1]);
      __builtin_amdgcn_s_setprio(0);
    }
    if (s + 1 < NS) {
      loadA1(s + 1);
      int nxt = cur ^ 1;
      *(uint4*)&Bh_s[nxt][lds0] = rbh; *(uint4*)&Bl_s[nxt][lds0] = rbl;
      if (s + 2 < NS) issueB(s + 2);
      BARRIER_NODRAIN();
    }
  }
  // epilogue: C/D layout col=lane&31, row=(g&3)+8*(g>>2)+4*(lane>>5)
#pragma unroll
  for (int t = 0; t < 2; ++t) {
    int mb = m0 + wm * 64 + t * 32;
    int n = n0 + wn * 32 + lm;
#pragma unroll
    for (int g = 0; g < 16; ++g) {
      int m = mb + (g & 3) + ((g >> 2) << 3) + (lh << 2);
      float val = acc[t][g] + bias[m];
      size_t oidx = ((size_t)b * CCH + m) * HWN + n;
      if (OUT == 0) {
        ((float*)Yv)[oidx] = val;
      } else if (OUT == 1) {
        ((__half*)Yv)[oidx] = __float2half(val);
      } else {
        size_t tix = ((size_t)b * HWN + n) * CCH + m;
        float xnv = bf2f(xnTh[tix]) + bf2f(xnTl[tix]);
        ((float*)Yv)[oidx] = val * xnv;
      }
    }
  }
}

// ---------------- 3x3 conv GEMM with dy-slab B reuse, BN=64 -----------------
// One image row per block; slab = row y0+dy x px in [-1,64] (edge columns
// pre-zeroed once), swept by the 3 dx taps via pixel-shifted ds_reads.
// Grid (64,3,8) = 1536 blocks = 6/CU for cross-block pipe overlap.
__global__ __launch_bounds__(256, 4) void mm9_kernel(
    const unsigned short* __restrict__ Ahg, const unsigned short* __restrict__ Alg,
    const float* __restrict__ bias,
    const unsigned short* __restrict__ Bhg, const unsigned short* __restrict__ Blg,
    const unsigned short* __restrict__ zp,
    float* __restrict__ Y) {
  __shared__ unsigned short Bh_s[66*LP], Bl_s[66*LP];   // 10.5 KB
  int tid = threadIdx.x;
  int b = blockIdx.z, m0 = blockIdx.y * 128;
  int y0 = blockIdx.x;
  int n0 = y0 << 6;
  int lane = tid & 63, wm = tid >> 7, wn = (tid >> 6) & 1;
  int lm = lane & 31, lh = lane >> 5;
  int mbb = blockIdx.y * 4 + wm * 2;
  int laneoff = lane << 3;

  v16f acc[2];
#pragma unroll
  for (int t = 0; t < 2; ++t)
#pragma unroll
    for (int g = 0; g < 16; ++g) acc[t][g] = 0.f;

  // zero the conv x-padding columns (px slots 0 and 65) once
  if (tid < 128) {
    int ch = tid & 31;
    int px = ((tid >> 5) & 1) ? 65 : 0;
    if (tid < 64) Bh_s[px * LP + ch] = 0; else Bl_s[px * LP + ch] = 0;
  }

  uint4 rs0, rs1;                    // slab prefetch (2 x 16B per thread)
  int px0s = tid >> 2, css = tid & 3;
  auto issueSlab = [&](int si2) {
    int dyi2 = si2 / 12, cidx2 = si2 - dyi2 * 12;
    int pyi = y0 + dyi2 - 1;
    bool ok = (unsigned)pyi < 64u;
    size_t go = ok ? (((size_t)b * HWN + pyi * 64 + px0s) * CCH + cidx2 * 32 + css * 8) : 0;
    rs0 = *(const uint4*)(ok ? Bhg + go : zp);
    rs1 = *(const uint4*)(ok ? Blg + go : zp);
  };
  auto writeSlab = [&]() {
    int dst = (px0s + 1) * LP + css * 8;
    *(uint4*)&Bh_s[dst] = rs0;
    *(uint4*)&Bl_s[dst] = rs1;
  };

  uint4 rA0h_h0, rA0l_h0, rA1h_h0, rA1l_h0;
  uint4 rA0h_h1, rA0l_h1, rA1h_h1, rA1l_h1;
  auto loadAh0 = [&](int fragcol) {
    size_t off = (((size_t)fragcol * 12 + mbb) << 9) + laneoff;
    rA0h_h0 = *(const uint4*)(Ahg + off);
    rA0l_h0 = *(const uint4*)(Alg + off);
    rA1h_h0 = *(const uint4*)(Ahg + off + 512);
    rA1l_h0 = *(const uint4*)(Alg + off + 512);
  };
  auto loadAh1 = [&](int fragcol) {
    size_t off = (((size_t)(fragcol + 1) * 12 + mbb) << 9) + laneoff;
    rA0h_h1 = *(const uint4*)(Ahg + off);
    rA0l_h1 = *(const uint4*)(Alg + off);
    rA1h_h1 = *(const uint4*)(Ahg + off + 512);
    rA1l_h1 = *(const uint4*)(Alg + off + 512);
  };
  auto ldS = [&](const unsigned short* base, int h, int dx) -> v8s {
    int px = wn * 32 + lm + dx + 1;
    return *(const v8s*)&base[px * LP + h * 16 + lh * 8];
  };

  // prologue
  issueSlab(0);
  writeSlab();
  issueSlab(1);
  loadAh0(0);          // tap r=0 (dy=-1,dx=-1), cidx 0, h0
  loadAh1(0);
  __syncthreads();

  int dyi = 0, cidx = 0;
  for (int si = 0; si < 36; ++si) {
    int rbase = dyi * 3;
    int ndyi = (cidx == 11) ? dyi + 1 : dyi;
    int ncidx = (cidx == 11) ? 0 : cidx + 1;
#pragma unroll
    for (int dxi = 0; dxi < 3; ++dxi) {
      const int dx = dxi - 1;
      bool last = (si == 35) && (dxi == 2);
      int nfc = (dxi < 2) ? ((rbase + dxi + 1) * 24 + cidx * 2)
                          : ((ndyi * 3) * 24 + ncidx * 2);
      {
        v8s b0h = ldS(Bh_s, 0, dx);
        v8s b0l = ldS(Bl_s, 0, dx);
        v8s a0h = as_v8s(rA0h_h0), a0l = as_v8s(rA0l_h0);
        v8s a1h = as_v8s(rA1h_h0), a1l = as_v8s(rA1l_h0);
        __builtin_amdgcn_s_setprio(1);
        acc[0] = MFMA_B16(a0h, b0h, acc[0]);
        acc[0] = MFMA_B16(a0h, b0l, acc[0]);
        acc[0] = MFMA_B16(a0l, b0h, acc[0]);
        acc[1] = MFMA_B16(a1h, b0h, acc[1]);
        acc[1] = MFMA_B16(a1h, b0l, acc[1]);
        acc[1] = MFMA_B16(a1l, b0h, acc[1]);
        __builtin_amdgcn_s_setprio(0);
      }
      if (!last) loadAh0(nfc);
      {
        v8s b0h = ldS(Bh_s, 1, dx);
        v8s b0l = ldS(Bl_s, 1, dx);
        v8s a0h = as_v8s(rA0h_h1), a0l = as_v8s(rA0l_h1);
        v8s a1h = as_v8s(rA1h_h1), a1l = as_v8s(rA1l_h1);
        __builtin_amdgcn_s_setprio(1);
        acc[0] = MFMA_B16(a0h, b0h, acc[0]);
        acc[0] = MFMA_B16(a0h, b0l, acc[0]);
        acc[0] = MFMA_B16(a0l, b0h, acc[0]);
        acc[1] = MFMA_B16(a1h, b0h, acc[1]);
        acc[1] = MFMA_B16(a1h, b0l, acc[1]);
        acc[1] = MFMA_B16(a1l, b0h, acc[1]);
        __builtin_amdgcn_s_setprio(0);
      }
      if (!last) loadAh1(nfc);
    }
    if (si < 35) {
      BARRIER_RAW();            // all slab reads consumed
      writeSlab();              // slab si+1 (vmcnt auto-wait on rs)
      if (si + 2 < 36) issueSlab(si + 2);
      BARRIER_NODRAIN();        // publish ds_writes; keep vmem in flight
    }
    dyi = ndyi; cidx = ncidx;
  }

  // epilogue
#pragma unroll
  for (int t = 0; t < 2; ++t) {
    int mb = m0 + wm * 64 + t * 32;
    int n = n0 + wn * 32 + lm;
#pragma unroll
    for (int g = 0; g < 16; ++g) {
      int m = mb + (g & 3) + ((g >> 2) << 3) + (lh << 2);
      Y[((size_t)b * CCH + m) * HWN + n] = acc[t][g] + bias[m];
    }
  }
}

// -------- FFT2 pass: 3 fused radix-4 stages (bit-reversed in, natural out) --
__device__ __forceinline__ void fft4_pass(float* zr, float* zi,
    const float* twr, const float* twi, int tid, int axis, float ds) {
#pragma unroll
  for (int s = 0; s < 3; ++s) {
    const int h = 1 << (2 * s);            // 1, 4, 16
#pragma unroll
    for (int tt = 0; tt < 4; ++tt) {
      int t = tid + (tt << 8);             // 0..1023: 64 lines x 16 radix-4 bf
      int line = t >> 4, bf = t & 15;
      int j  = bf & (h - 1);
      int i0 = ((bf >> (2 * s)) << (2 * s + 2)) + j;
      int e1 = j << (5 - 2 * s);
      int e2 = j << (4 - 2 * s);
      float w1r = twr[e1], w1i = ds * twi[e1];
      float w2r = twr[e2], w2i = ds * twi[e2];
      int A0, st;
      if (axis == 0) { A0 = line * FFTP + i0; st = h; }
      else           { A0 = i0 * FFTP + line; st = h * FFTP; }
      int A1 = A0 + st, A2 = A1 + st, A3 = A2 + st;
      float x0r = zr[A0], x0i = zi[A0];
      float x1r = zr[A1], x1i = zi[A1];
      float x2r = zr[A2], x2i = zi[A2];
      float x3r = zr[A3], x3i = zi[A3];
      float t1r = x1r*w1r - x1i*w1i, t1i = x1r*w1i + x1i*w1r;
      float t3r = x3r*w1r - x3i*w1i, t3i = x3r*w1i + x3i*w1r;
      float u0r = x0r + t1r, u0i = x0i + t1i;
      float u1r = x0r - t1r, u1i = x0i - t1i;
      float u2r = x2r + t3r, u2i = x2i + t3i;
      float u3r = x2r - t3r, u3i = x2i - t3i;
      float c2r = u2r*w2r - u2i*w2i, c2i = u2r*w2i + u2i*w2r;
      float c3r = u3r*w2r - u3i*w2i, c3i = u3r*w2i + u3i*w2r;
      zr[A0] = u0r + c2r;      zi[A0] = u0i + c2i;
      zr[A2] = u0r - c2r;      zi[A2] = u0i - c2i;
      zr[A1] = u1r + ds*c3i;   zi[A1] = u1i - ds*c3r;
      zr[A3] = u1r - ds*c3i;   zi[A3] = u1i + ds*c3r;
    }
    __syncthreads();
  }
}

// --------- fused: circ-conv(q,k) via FFT + exact top-k + softmax + *v -------
// F4 may alias q (block reads its q range fully before writing F4).
__global__ __launch_bounds__(256) void fft_topk_kernel(
    const float* q, const float* __restrict__ kkb,
    const __half* __restrict__ v, float* F4) {
  __shared__ float zr[64 * FFTP], zi[64 * FFTP];
  __shared__ float twr[32], twi[32];
  __shared__ unsigned hist[4][256];        // per-wave sub-histograms
  __shared__ unsigned su2[2];
  __shared__ unsigned wtot[4];
  __shared__ float sred[5];
  int tid = threadIdx.x;
  int lane = tid & 63, w = tid >> 6;
  size_t base = (size_t)blockIdx.x * HWN;
  for (int i = tid; i < HWN; i += 256) {
    int y = i >> 6, x = i & 63;
    int slot = br6(y) * FFTP + br6(x);
    zr[slot] = q[base + i];
    zi[slot] = kkb[base + i];
  }
  if (tid < 32) {
    float ang = (float)tid * 0.0981747704246810387f;  // 2*pi/64
    twr[tid] = cosf(ang);
    twi[tid] = -sinf(ang);                            // forward e^{-i theta}
  }
  __syncthreads();
  fft4_pass(zr, zi, twr, twi, tid, 0, 1.f);
  fft4_pass(zr, zi, twr, twi, tid, 1, 1.f);
  // split Z into Fq,Fk via Hermitian symmetry; P = Fq*Fk
  float prr[16], pir[16];
#pragma unroll
  for (int c = 0; c < 16; c++) {
    int i = tid + (c << 8);
    int ky = i >> 6, kx = i & 63;
    float sr = zr[ky * FFTP + kx], si = zi[ky * FFTP + kx];
    int kyn = (64 - ky) & 63, kxn = (64 - kx) & 63;
    float nr = zr[kyn * FFTP + kxn], ni = zi[kyn * FFTP + kxn];
    float fqr = 0.5f * (sr + nr), fqi = 0.5f * (si - ni);
    float fkr = 0.5f * (si + ni), fki = 0.5f * (nr - sr);
    prr[c] = fqr * fkr - fqi * fki;
    pir[c] = fqr * fki + fqi * fkr;
  }
  __syncthreads();
#pragma unroll
  for (int c = 0; c < 16; c++) {
    int i = tid + (c << 8);
    int ky = i >> 6, kx = i & 63;
    int slot = br6(ky) * FFTP + br6(kx);
    zr[slot] = prr[c];
    zi[slot] = pir[c];
  }
  __syncthreads();
  fft4_pass(zr, zi, twr, twi, tid, 0, -1.f);
  fft4_pass(zr, zi, twr, twi, tid, 1, -1.f);
  // pull this thread's 16 A values into registers; LDS not re-read after this
  const float scale = 1.0f / 4096.0f;
  float a[16];
  unsigned key[16];
  float mx = -3.0e38f;
#pragma unroll
  for (int c = 0; c < 16; c++) {
    int i = tid + (c << 8);
    a[c] = zr[(i >> 6) * FFTP + (i & 63)] * scale;
    key[c] = f2key(a[c]);
    mx = fmaxf(mx, a[c]);
  }
  mx = wave_max(mx);
  if (lane == 0) sred[w] = mx;
  __syncthreads();
  if (tid == 0) sred[4] = fmaxf(fmaxf(sred[0], sred[1]), fmaxf(sred[2], sred[3]));
  __syncthreads();
  float am = sred[4];
  // 4-pass byte radix select (exact 512th-largest key), shuffle-based scan
  unsigned prefix = 0; int kr = KSEL;
  for (int pass = 0; pass < 4; pass++) {
    int shift = 24 - (pass << 3);
#pragma unroll
    for (int ww = 0; ww < 4; ++ww) hist[ww][tid] = 0;
    __syncthreads();
#pragma unroll
    for (int c = 0; c < 16; c++) {
      unsigned u = key[c];
      if (((u ^ prefix) >> shift) <= 0xFFu)
        atomicAdd(&hist[w][(u >> shift) & 255u], 1u);
    }
    __syncthreads();
    unsigned xv = hist[0][tid] + hist[1][tid] + hist[2][tid] + hist[3][tid];
#pragma unroll
    for (int o = 1; o < 64; o <<= 1) {      // intra-wave suffix scan
      unsigned t2 = __shfl_down(xv, o, 64);
      if (lane + o < 64) xv += t2;
    }
    if (lane == 0) wtot[w] = xv;
    __syncthreads();
    for (int ww = w + 1; ww < 4; ++ww) xv += wtot[ww];
    hist[0][tid] = xv;                       // S[t] = #keys with byte >= t
    __syncthreads();
    unsigned sv = xv;
    unsigned svn = (tid < 255) ? hist[0][tid + 1] : 0u;
    if (sv >= (unsigned)kr && svn < (unsigned)kr) { su2[0] = (unsigned)tid; su2[1] = svn; }
    __syncthreads();
    prefix |= su2[0] << shift;
    kr -= (int)su2[1];
  }
  unsigned thr = prefix;
  float lsum = 0.f;
#pragma unroll
  for (int c = 0; c < 16; c++)
    if (key[c] >= thr) lsum += expf(a[c] - am);
  lsum = wave_sum(lsum);
  if (lane == 0) sred[w] = lsum;
  __syncthreads();
  if (tid == 0) sred[4] = 1.0f / (sred[0] + sred[1] + sred[2] + sred[3]);
  __syncthreads();
  float inv = sred[4];
#pragma unroll
  for (int c = 0; c < 16; c++) {
    int i = tid + (c << 8);
    float wgt = (key[c] >= thr) ? expf(a[c] - am) * inv : 0.f;
    F4[base + i] = __half2float(v[base + i]) * wgt;
  }
}

extern "C" void kernel_launch(void* const* d_in, const int* in_sizes, int n_in,
                              void* d_out, int out_size, void* d_ws, size_t ws_size,
                              hipStream_t stream) {
  const float* x     = (const float*)d_in[0];
  const float* gamma = (const float*)d_in[1];
  const float* beta  = (const float*)d_in[2];
  const float* wq    = (const float*)d_in[3];
  const float* bq    = (const float*)d_in[4];
  const float* wk    = (const float*)d_in[5];
  const float* bk    = (const float*)d_in[6];
  const float* wv    = (const float*)d_in[7];
  const float* bv    = (const float*)d_in[8];
  const float* wf    = (const float*)d_in[9];
  const float* bf    = (const float*)d_in[10];

  const size_t NEL = (size_t)BATCH * CCH * HWN;   // 12,582,912
  const size_t WSZ = (size_t)CCH * CCH;           // 147,456

  unsigned short* xnTh = (unsigned short*)d_ws;        // bf16 NHWC hi
  unsigned short* xnTl = xnTh + NEL;                   // bf16 NHWC lo
  float*  qC  = (float*)(xnTl + NEL);                  // q fp32 -> F4 fp32
  float*  kD  = qC + NEL;                              // k fp32 -> F4T hi/lo
  __half* vE  = (__half*)(kD + NEL);                   // v fp16
  unsigned short* W = (unsigned short*)(vE + NEL);
  unsigned short* Wqh = W;
  unsigned short* Wql = Wqh + WSZ;
  unsigned short* Wvh = Wql + WSZ;
  unsigned short* Wvl = Wvh + WSZ;
  unsigned short* Wfh = Wvl + WSZ;
  unsigned short* Wfl = Wfh + WSZ;
  unsigned short* Wkh = Wfl + WSZ;                     // 9*147456
  unsigned short* Wkl = Wkh + 9 * WSZ;
  float2* gs = (float2*)(Wkl + 9 * WSZ);
  unsigned short* zp = (unsigned short*)(gs + BATCH * NG);  // 16B zero page
  unsigned short* F4Th = (unsigned short*)kD;          // reuse k region
  unsigned short* F4Tl = F4Th + NEL;

  pack_split_k<<<dim3(576), dim3(256), 0, stream>>>(wq, Wqh, Wql, (int)WSZ);
  pack_split_k<<<dim3(576), dim3(256), 0, stream>>>(wv, Wvh, Wvl, (int)WSZ);
  pack_split_k<<<dim3(576), dim3(256), 0, stream>>>(wf, Wfh, Wfl, (int)WSZ);
  pack9_k<<<dim3(576, 9), dim3(256), 0, stream>>>(wk, Wkh, Wkl);
  stats_kernel<<<dim3(BATCH * NG), dim3(256), 0, stream>>>(x, gs, zp);
  trans_kernel<1, 1><<<dim3(64, 6, BATCH), dim3(256), 0, stream>>>(
      x, gs, gamma, beta, xnTh, xnTl);

  dim3 gm(64, 3, BATCH);                               // BN=64: 1536 blocks
  mm_kernel<1, 0><<<gm, dim3(256), 0, stream>>>(Wqh, Wql, bq, xnTh, xnTl,
                                                nullptr, nullptr, qC);
  mm9_kernel<<<gm, dim3(256), 0, stream>>>(Wkh, Wkl, bk, xnTh, xnTl, zp, kD);
  mm_kernel<1, 1><<<gm, dim3(256), 0, stream>>>(Wvh, Wvl, bv, xnTh, xnTl,
                                                nullptr, nullptr, vE);

  fft_topk_kernel<<<dim3(BATCH * CCH), dim3(256), 0, stream>>>(qC, kD, vE, qC);

  trans_kernel<0, 1><<<dim3(64, 6, BATCH), dim3(256), 0, stream>>>(
      qC, nullptr, nullptr, nullptr, F4Th, F4Tl);

  mm_kernel<1, 2><<<gm, dim3(256), 0, stream>>>(Wfh, Wfl, bf, F4Th, F4Tl,
                                                xnTh, xnTl, d_out);
}

// Round 8
// 616.287 us; speedup vs baseline: 1.1038x; 1.1038x over previous
//
#include <hip/hip_runtime.h>
#include <hip/hip_fp16.h>
#include <math.h>

#define CCH  384
#define BATCH 8
#define HWN  4096
#define NG   32
#define CPG  12
#define KSEL 512
#define FFTP 65   // FFT LDS pitch
#define LP   40   // mm LDS pitch (bf16 units)

typedef short v8s  __attribute__((ext_vector_type(8)));   // 8 bf16 (4 VGPRs)
typedef float v16f __attribute__((ext_vector_type(16)));  // 32x32 acc

#define MFMA_B16(A_,B_,C_) __builtin_amdgcn_mfma_f32_32x32x16_bf16((A_),(B_),(C_),0,0,0)

// barrier WITHOUT the vmcnt(0) drain __syncthreads would emit: ds_writes are
// published (lgkmcnt(0)) but global-load prefetches stay in flight across the
// barrier; consumers wait on their own data via compiler-inserted vmcnt(N).
#define BARRIER_NODRAIN() asm volatile("s_waitcnt lgkmcnt(0)\n\ts_barrier" ::: "memory")
// raw barrier: nothing drained (ds_reads already consumed by MFMAs).
#define BARRIER_RAW() asm volatile("s_barrier" ::: "memory")

__device__ __forceinline__ v8s as_v8s(uint4 u) {
  union { uint4 u4; v8s v; } c; c.u4 = u; return c.v;
}
__device__ __forceinline__ unsigned br6(unsigned i) {
  return ((i&1u)<<5)|((i&2u)<<3)|((i&4u)<<1)|((i&8u)>>1)|((i&16u)>>3)|((i&32u)>>5);
}
__device__ __forceinline__ unsigned f2key(float f) {
  unsigned u = __float_as_uint(f);
  return (u & 0x80000000u) ? ~u : (u | 0x80000000u);
}
__device__ __forceinline__ float wave_max(float v) {
#pragma unroll
  for (int o = 32; o > 0; o >>= 1) v = fmaxf(v, __shfl_down(v, o, 64));
  return v;
}
__device__ __forceinline__ float wave_sum(float v) {
#pragma unroll
  for (int o = 32; o > 0; o >>= 1) v += __shfl_down(v, o, 64);
  return v;
}
__device__ __forceinline__ unsigned short bf16_rne(float f) {
  unsigned u = __float_as_uint(f);
  return (unsigned short)((u + 0x7fffu + ((u >> 16) & 1u)) >> 16);
}
__device__ __forceinline__ float bf2f(unsigned short h) {
  return __uint_as_float(((unsigned)h) << 16);
}

// ---------------- group stats (mu, rsqrt(var+eps)) per (b,g) ----------------
__global__ __launch_bounds__(256) void stats_kernel(const float* __restrict__ x,
                                                    float2* __restrict__ gs,
                                                    unsigned short* __restrict__ zp) {
  int b = blockIdx.x >> 5, g = blockIdx.x & 31;
  if (blockIdx.x == 0 && threadIdx.x < 8) zp[threadIdx.x] = 0;  // zero page
  size_t base = ((size_t)b * CCH + (size_t)g * CPG) * HWN;
  const float4* xp = (const float4*)(x + base);
  int tid = threadIdx.x;
  const int N4 = CPG * HWN / 4;
  float s = 0.f, ss = 0.f;
  for (int i = tid; i < N4; i += 256) {
    float4 v = xp[i];
    s  += (v.x + v.y) + (v.z + v.w);
    ss += (v.x*v.x + v.y*v.y) + (v.z*v.z + v.w*v.w);
  }
  s = wave_sum(s); ss = wave_sum(ss);
  __shared__ float sb[4], qb[4];
  if ((tid & 63) == 0) { sb[tid >> 6] = s; qb[tid >> 6] = ss; }
  __syncthreads();
  if (tid == 0) {
    float S = sb[0]+sb[1]+sb[2]+sb[3], Q = qb[0]+qb[1]+qb[2]+qb[3];
    float inv = 1.0f / (float)(CPG * HWN);
    float mu = S * inv;
    float var = Q * inv - mu * mu;
    gs[blockIdx.x] = make_float2(mu, rsqrtf(var + 1e-5f));
  }
}

// ------- weight pack: fp32 -> bf16 hi + lo, in MFMA A-fragment order --------
// frag layout: frag_id = (r*24 + kc)*12 + mb   (kc = K/16 chunk, mb = M/32)
// within frag: lane l (0..63) holds A[mb*32 + (l&31)][kc*16 + (l>>5)*8 + j]
__global__ __launch_bounds__(256) void pack_split_k(const float* __restrict__ w,
    unsigned short* __restrict__ hi, unsigned short* __restrict__ lo, int n) {
  int i = blockIdx.x * 256 + threadIdx.x;
  if (i >= n) return;
  float f = w[i];
  int m = i / 384, ci = i - m * 384;
  int kc = ci >> 4, tt = ci & 15;
  int mb = m >> 5, lm2 = m & 31;
  int l = ((tt >> 3) << 5) | lm2;
  int j = tt & 7;
  size_t o = (((size_t)kc * 12 + mb) << 9) + ((size_t)l << 3) + j;
  unsigned short h = bf16_rne(f);
  hi[o] = h;
  lo[o] = bf16_rne(f - bf2f(h));
}
// wk[m][ci][r] (r=3x3 tap) -> fragment-packed planes per r
__global__ __launch_bounds__(256) void pack9_k(const float* __restrict__ w,
    unsigned short* __restrict__ hi, unsigned short* __restrict__ lo) {
  int i = blockIdx.x * 256 + threadIdx.x;     // 0..147455 == m*384+ci
  int r = blockIdx.y;
  float f = w[(size_t)i * 9 + r];
  int m = i / 384, ci = i - m * 384;
  int kc = ci >> 4, tt = ci & 15;
  int mb = m >> 5, lm2 = m & 31;
  int l = ((tt >> 3) << 5) | lm2;
  int j = tt & 7;
  size_t o = (((size_t)(r * 24 + kc) * 12 + mb) << 9) + ((size_t)l << 3) + j;
  unsigned short h = bf16_rne(f);
  hi[o] = h;
  lo[o] = bf16_rne(f - bf2f(h));
}

// ---- transpose NCHW fp32 -> NHWC bf16 hi(/lo); FUSE=1 applies GroupNorm ----
template<int FUSE, int SPLIT>
__global__ __launch_bounds__(256) void trans_kernel(const float* __restrict__ in,
    const float2* __restrict__ gs, const float* __restrict__ gamma,
    const float* __restrict__ beta,
    unsigned short* __restrict__ oh, unsigned short* __restrict__ ol) {
  __shared__ float ts[64][65];
  int tid = threadIdx.x;
  int b = blockIdx.z, c0 = blockIdx.y * 64, p0 = blockIdx.x * 64;
#pragma unroll
  for (int i = 0; i < 4; ++i) {
    int idx = tid + (i << 8);
    int row = idx >> 4, col = (idx & 15) << 2;
    float4 v = *(const float4*)&in[((size_t)b*CCH + c0 + row)*HWN + p0 + col];
    if (FUSE) {
      int c = c0 + row;
      float2 st = gs[(b << 5) + c / CPG];
      float a = gamma[c] * st.y, bb = beta[c] - st.x * a;
      v.x = v.x*a+bb; v.y = v.y*a+bb; v.z = v.z*a+bb; v.w = v.w*a+bb;
    }
    ts[row][col] = v.x; ts[row][col+1] = v.y; ts[row][col+2] = v.z; ts[row][col+3] = v.w;
  }
  __syncthreads();
#pragma unroll
  for (int i = 0; i < 2; ++i) {
    int idx = tid + (i << 8);
    int p = idx >> 3, cgp = (idx & 7) << 3;
    unsigned short h8[8] __attribute__((aligned(16)));
    unsigned short l8[8] __attribute__((aligned(16)));
#pragma unroll
    for (int j = 0; j < 8; ++j) {
      float f = ts[cgp + j][p];
      unsigned short hb = bf16_rne(f);
      h8[j] = hb;
      if (SPLIT) l8[j] = bf16_rne(f - bf2f(hb));
    }
    size_t o = ((size_t)b*HWN + p0 + p)*CCH + c0 + cgp;
    *(uint4*)&oh[o] = *(const uint4*)h8;
    if (SPLIT) *(uint4*)&ol[o] = *(const uint4*)l8;
  }
}

// ------------- MFMA GEMM (1x1 convs), bf16 2-term split, round-1 form -------
// A register-direct from global (fragment-packed), B reg->ds_write staged,
// double-buffered, BARRIER_NODRAIN per step.
// OUT: 0 = fp32 NCHW, 1 = fp16 NCHW, 2 = fp32 NCHW * (xnT_h+xnT_l) -> d_out
template<int TAPS, int OUT>
__global__ __launch_bounds__(256, 3) void mm_kernel(
    const unsigned short* __restrict__ Ahg, const unsigned short* __restrict__ Alg,
    const float* __restrict__ bias,
    const unsigned short* __restrict__ Bhg, const unsigned short* __restrict__ Blg,
    const unsigned short* __restrict__ xnTh, const unsigned short* __restrict__ xnTl,
    void* __restrict__ Yv) {
  __shared__ unsigned short Bh_s[2][128*LP], Bl_s[2][128*LP];
  int tid = threadIdx.x;
  int b = blockIdx.z, m0 = blockIdx.y * 128, n0 = blockIdx.x * 128;
  int y0 = blockIdx.x * 2;                 // tile = image rows y0, y0+1
  int u0row = tid >> 2, cg = tid & 3;      // staging atom: 16B = 8 bf16
  int lds0 = u0row * LP + cg * 8, lds1 = lds0 + 64 * LP;
  int lane = tid & 63, wm = tid >> 7, wn = (tid >> 6) & 1;
  int lm = lane & 31, lh = lane >> 5;
  int brow = (wn * 64 + lm) * LP;
  int mbb = blockIdx.y * 4 + wm * 2;       // M/32 block base for this wave
  int laneoff = lane << 3;

  v16f acc[2][2];
#pragma unroll
  for (int t = 0; t < 2; ++t)
#pragma unroll
    for (int s = 0; s < 2; ++s)
#pragma unroll
      for (int g = 0; g < 16; ++g) acc[t][s][g] = 0.f;

  const int NS = TAPS * 12;
  uint4 rb0h, rb0l, rb1h, rb1l;
  uint4 rA0h_h0, rA0l_h0, rA1h_h0, rA1l_h0;   // step-current A frags, h=0
  uint4 rA0h_h1, rA0l_h1, rA1h_h1, rA1l_h1;   // step-current A frags, h=1

  auto issueB = [&](int s) {
    int c0 = s * 32;
    int px = u0row;
    int py0 = y0, py1 = py0 + 1;
    size_t boff0 = ((size_t)b * HWN + py0 * 64 + px) * CCH + cg * 8 + c0;
    size_t boff1 = ((size_t)b * HWN + py1 * 64 + px) * CCH + cg * 8 + c0;
    rb0h = *(const uint4*)(Bhg + boff0);
    rb0l = *(const uint4*)(Blg + boff0);
    rb1h = *(const uint4*)(Bhg + boff1);
    rb1l = *(const uint4*)(Blg + boff1);
  };
  auto loadA0 = [&](int s) {                 // fragments for half-step h=0
    int fragcol = s * 2;
    size_t off = (((size_t)fragcol * 12 + mbb) << 9) + laneoff;
    rA0h_h0 = *(const uint4*)(Ahg + off);
    rA0l_h0 = *(const uint4*)(Alg + off);
    rA1h_h0 = *(const uint4*)(Ahg + off + 512);
    rA1l_h0 = *(const uint4*)(Alg + off + 512);
  };
  auto loadA1 = [&](int s) {                 // fragments for half-step h=1
    int fragcol = s * 2 + 1;
    size_t off = (((size_t)fragcol * 12 + mbb) << 9) + laneoff;
    rA0h_h1 = *(const uint4*)(Ahg + off);
    rA0l_h1 = *(const uint4*)(Alg + off);
    rA1h_h1 = *(const uint4*)(Ahg + off + 512);
    rA1l_h1 = *(const uint4*)(Alg + off + 512);
  };

  // prologue: B(0) -> buf0, A(0) -> regs, B(1) -> regs
  issueB(0);
  loadA0(0); loadA1(0);
  *(uint4*)&Bh_s[0][lds0] = rb0h; *(uint4*)&Bl_s[0][lds0] = rb0l;
  *(uint4*)&Bh_s[0][lds1] = rb1h; *(uint4*)&Bl_s[0][lds1] = rb1l;
  issueB(1);
  BARRIER_NODRAIN();

  for (int s = 0; s < NS; ++s) {
    const int cur = s & 1;
    const unsigned short* Bh = &Bh_s[cur][0];
    const unsigned short* Bl = &Bl_s[cur][0];
    {
      int co = lh << 3;
      v8s b0h = *(const v8s*)&Bh[brow + co];
      v8s b0l = *(const v8s*)&Bl[brow + co];
      v8s b1h = *(const v8s*)&Bh[brow + 32*LP + co];
      v8s b1l = *(const v8s*)&Bl[brow + 32*LP + co];
      v8s a0h = as_v8s(rA0h_h0), a0l = as_v8s(rA0l_h0);
      v8s a1h = as_v8s(rA1h_h0), a1l = as_v8s(rA1l_h0);
      __builtin_amdgcn_s_setprio(1);
      acc[0][0] = MFMA_B16(a0h, b0h, acc[0][0]);
      acc[0][0] = MFMA_B16(a0h, b0l, acc[0][0]);
      acc[0][0] = MFMA_B16(a0l, b0h, acc[0][0]);
      acc[0][1] = MFMA_B16(a0h, b1h, acc[0][1]);
      acc[0][1] = MFMA_B16(a0h, b1l, acc[0][1]);
      acc[0][1] = MFMA_B16(a0l, b1h, acc[0][1]);
      acc[1][0] = MFMA_B16(a1h, b0h, acc[1][0]);
      acc[1][0] = MFMA_B16(a1h, b0l, acc[1][0]);
      acc[1][0] = MFMA_B16(a1l, b0h, acc[1][0]);
      acc[1][1] = MFMA_B16(a1h, b1h, acc[1][1]);
      acc[1][1] = MFMA_B16(a1h, b1l, acc[1][1]);
      acc[1][1] = MFMA_B16(a1l, b1h, acc[1][1]);
      __builtin_amdgcn_s_setprio(0);
    }
    if (s + 1 < NS) loadA0(s + 1);   // latency hides under h=1 MFMAs
    {
      int co = 16 + (lh << 3);
      v8s b0h = *(const v8s*)&Bh[brow + co];
      v8s b0l = *(const v8s*)&Bl[brow + co];
      v8s b1h = *(const v8s*)&Bh[brow + 32*LP + co];
      v8s b1l = *(const v8s*)&Bl[brow + 32*LP + co];
      v8s a0h = as_v8s(rA0h_h1), a0l = as_v8s(rA0l_h1);
      v8s a1h = as_v8s(rA1h_h1), a1l = as_v8s(rA1l_h1);
      __builtin_amdgcn_s_setprio(1);
      acc[0][0] = MFMA_B16(a0h, b0h, acc[0][0]);
      acc[0][0] = MFMA_B16(a0h, b0l, acc[0][0]);
      acc[0][0] = MFMA_B16(a0l, b0h, acc[0][0]);
      acc[0][1] = MFMA_B16(a0h, b1h, acc[0][1]);
      acc[0][1] = MFMA_B16(a0h, b1l, acc[0][1]);
      acc[0][1] = MFMA_B16(a0l, b1h, acc[0][1]);
      acc[1][0] = MFMA_B16(a1h, b0h, acc[1][0]);
      acc[1][0] = MFMA_B16(a1h, b0l, acc[1][0]);
      acc[1][0] = MFMA_B16(a1l, b0h, acc[1][0]);
      acc[1][1] = MFMA_B16(a1h, b1h, acc[1][1]);
      acc[1][1] = MFMA_B16(a1h, b1l, acc[1][1]);
      acc[1][1] = MFMA_B16(a1l, b1h, acc[1][1]);
      __builtin_amdgcn_s_setprio(0);
    }
    if (s + 1 < NS) {
      loadA1(s + 1);
      int nxt = cur ^ 1;
      *(uint4*)&Bh_s[nxt][lds0] = rb0h; *(uint4*)&Bl_s[nxt][lds0] = rb0l;
      *(uint4*)&Bh_s[nxt][lds1] = rb1h; *(uint4*)&Bl_s[nxt][lds1] = rb1l;
      if (s + 2 < NS) issueB(s + 2);
      BARRIER_NODRAIN();
    }
  }
  // epilogue: C/D layout col=lane&31, row=(g&3)+8*(g>>2)+4*(lane>>5)
#pragma unroll
  for (int t = 0; t < 2; ++t) {
    int mb = m0 + wm * 64 + t * 32;
#pragma unroll
    for (int s = 0; s < 2; ++s) {
      int n = n0 + wn * 64 + s * 32 + lm;
#pragma unroll
      for (int g = 0; g < 16; ++g) {
        int m = mb + (g & 3) + ((g >> 2) << 3) + (lh << 2);
        float val = acc[t][s][g] + bias[m];
        size_t oidx = ((size_t)b * CCH + m) * HWN + n;
        if (OUT == 0) {
          ((float*)Yv)[oidx] = val;
        } else if (OUT == 1) {
          ((__half*)Yv)[oidx] = __float2half(val);
        } else {
          size_t tix = ((size_t)b * HWN + n) * CCH + m;
          float xnv = bf2f(xnTh[tix]) + bf2f(xnTl[tix]);
          ((float*)Yv)[oidx] = val * xnv;
        }
      }
    }
  }
}

// ---------------- 3x3 conv GEMM with dy-slab B reuse ------------------------
// Per (dy, K-chunk): stage input rows {y0+dy, y0+1+dy} x px in [-1,64] (edge
// columns pre-zeroed once -- conv x-padding is constant) into one LDS slab,
// then sweep the 3 dx taps against it via pixel-shifted ds_reads.  B global
// traffic / 2.8, one stage per 72 MFMAs (2 barriers per slab, 36 slabs).
// A stays register-direct (round-1 single-set prefetch; no reg double-buffer).
__global__ __launch_bounds__(256, 3) void mm9_kernel(
    const unsigned short* __restrict__ Ahg, const unsigned short* __restrict__ Alg,
    const float* __restrict__ bias,
    const unsigned short* __restrict__ Bhg, const unsigned short* __restrict__ Blg,
    const unsigned short* __restrict__ zp,
    float* __restrict__ Y) {
  __shared__ unsigned short Bh_s[2*66*LP], Bl_s[2*66*LP];   // 2 x 10560 B
  int tid = threadIdx.x;
  int b = blockIdx.z, m0 = blockIdx.y * 128, n0 = blockIdx.x * 128;
  int y0 = blockIdx.x * 2;
  int lane = tid & 63, wm = tid >> 7, wn = (tid >> 6) & 1;
  int lm = lane & 31, lh = lane >> 5;
  int mbb = blockIdx.y * 4 + wm * 2;
  int laneoff = lane << 3;

  v16f acc[2][2];
#pragma unroll
  for (int t = 0; t < 2; ++t)
#pragma unroll
    for (int s = 0; s < 2; ++s)
#pragma unroll
      for (int g = 0; g < 16; ++g) acc[t][s][g] = 0.f;

  // zero the conv x-padding columns (px slots 0 and 65) once
  if (tid < 128) {
    int py = (tid >> 6) & 1, e = (tid >> 5) & 1, ch = tid & 31;
    int px = e ? 65 : 0;
    Bh_s[(py*66 + px)*LP + ch] = 0;
    Bl_s[(py*66 + px)*LP + ch] = 0;
  }

  uint4 rs0, rs1, rs2, rs3;   // slab prefetch regs (1024 chunks / 256 thr)
  auto issueSlab = [&](int si2) {
    int dyi2 = si2 / 12, cidx2 = si2 - dyi2 * 12;
    int dy = dyi2 - 1;
#pragma unroll
    for (int k2 = 0; k2 < 4; ++k2) {
      int cid = tid + (k2 << 8);
      int rr = cid & 511;
      int py = rr >> 8;
      int r3 = rr & 255;
      int px0 = r3 >> 2, cs = r3 & 3;
      int pyi = y0 + dy + py;
      bool ok = (unsigned)pyi < 64u;
      size_t go = ok ? (((size_t)b * HWN + pyi * 64 + px0) * CCH + cidx2 * 32 + cs * 8) : 0;
      const unsigned short* src = (cid < 512) ? (ok ? Bhg + go : zp)
                                              : (ok ? Blg + go : zp);
      uint4 v = *(const uint4*)src;
      if (k2 == 0) rs0 = v; else if (k2 == 1) rs1 = v;
      else if (k2 == 2) rs2 = v; else rs3 = v;
    }
  };
  auto writeSlab = [&]() {
#pragma unroll
    for (int k2 = 0; k2 < 4; ++k2) {
      int cid = tid + (k2 << 8);
      int rr = cid & 511;
      int py = rr >> 8;
      int r3 = rr & 255;
      int px0 = r3 >> 2, cs = r3 & 3;
      int dst = (py * 66 + px0 + 1) * LP + cs * 8;
      unsigned short* arr = (cid < 512) ? Bh_s : Bl_s;
      uint4 v = (k2 == 0) ? rs0 : (k2 == 1) ? rs1 : (k2 == 2) ? rs2 : rs3;
      *(uint4*)&arr[dst] = v;
    }
  };

  uint4 rA0h_h0, rA0l_h0, rA1h_h0, rA1l_h0;
  uint4 rA0h_h1, rA0l_h1, rA1h_h1, rA1l_h1;
  auto loadAh0 = [&](int fragcol) {
    size_t off = (((size_t)fragcol * 12 + mbb) << 9) + laneoff;
    rA0h_h0 = *(const uint4*)(Ahg + off);
    rA0l_h0 = *(const uint4*)(Alg + off);
    rA1h_h0 = *(const uint4*)(Ahg + off + 512);
    rA1l_h0 = *(const uint4*)(Alg + off + 512);
  };
  auto loadAh1 = [&](int fragcol) {
    size_t off = (((size_t)(fragcol + 1) * 12 + mbb) << 9) + laneoff;
    rA0h_h1 = *(const uint4*)(Ahg + off);
    rA0l_h1 = *(const uint4*)(Alg + off);
    rA1h_h1 = *(const uint4*)(Ahg + off + 512);
    rA1l_h1 = *(const uint4*)(Alg + off + 512);
  };
  // slab read: wave wn covers output row y0+wn -> slab py row wn
  auto ldS = [&](const unsigned short* base, int sb, int h, int dx) -> v8s {
    int px = sb * 32 + lm + dx + 1;
    return *(const v8s*)&base[(wn * 66 + px) * LP + h * 16 + lh * 8];
  };

  // prologue
  issueSlab(0);
  writeSlab();
  issueSlab(1);
  loadAh0(0);          // tap r=0 (dy=-1,dx=-1), cidx 0, h0
  loadAh1(0);
  __syncthreads();

  int dyi = 0, cidx = 0;
  for (int si = 0; si < 36; ++si) {
    int rbase = dyi * 3;
    int ndyi = (cidx == 11) ? dyi + 1 : dyi;
    int ncidx = (cidx == 11) ? 0 : cidx + 1;
#pragma unroll
    for (int dxi = 0; dxi < 3; ++dxi) {
      const int dx = dxi - 1;
      bool last = (si == 35) && (dxi == 2);
      int nfc = (dxi < 2) ? ((rbase + dxi + 1) * 24 + cidx * 2)
                          : ((ndyi * 3) * 24 + ncidx * 2);
      {
        v8s b0h = ldS(Bh_s, 0, 0, dx), b1h = ldS(Bh_s, 1, 0, dx);
        v8s b0l = ldS(Bl_s, 0, 0, dx), b1l = ldS(Bl_s, 1, 0, dx);
        v8s a0h = as_v8s(rA0h_h0), a0l = as_v8s(rA0l_h0);
        v8s a1h = as_v8s(rA1h_h0), a1l = as_v8s(rA1l_h0);
        __builtin_amdgcn_s_setprio(1);
        acc[0][0] = MFMA_B16(a0h, b0h, acc[0][0]);
        acc[0][0] = MFMA_B16(a0h, b0l, acc[0][0]);
        acc[0][0] = MFMA_B16(a0l, b0h, acc[0][0]);
        acc[0][1] = MFMA_B16(a0h, b1h, acc[0][1]);
        acc[0][1] = MFMA_B16(a0h, b1l, acc[0][1]);
        acc[0][1] = MFMA_B16(a0l, b1h, acc[0][1]);
        acc[1][0] = MFMA_B16(a1h, b0h, acc[1][0]);
        acc[1][0] = MFMA_B16(a1h, b0l, acc[1][0]);
        acc[1][0] = MFMA_B16(a1l, b0h, acc[1][0]);
        acc[1][1] = MFMA_B16(a1h, b1h, acc[1][1]);
        acc[1][1] = MFMA_B16(a1h, b1l, acc[1][1]);
        acc[1][1] = MFMA_B16(a1l, b1h, acc[1][1]);
        __builtin_amdgcn_s_setprio(0);
      }
      if (!last) loadAh0(nfc);
      {
        v8s b0h = ldS(Bh_s, 0, 1, dx), b1h = ldS(Bh_s, 1, 1, dx);
        v8s b0l = ldS(Bl_s, 0, 1, dx), b1l = ldS(Bl_s, 1, 1, dx);
        v8s a0h = as_v8s(rA0h_h1), a0l = as_v8s(rA0l_h1);
        v8s a1h = as_v8s(rA1h_h1), a1l = as_v8s(rA1l_h1);
        __builtin_amdgcn_s_setprio(1);
        acc[0][0] = MFMA_B16(a0h, b0h, acc[0][0]);
        acc[0][0] = MFMA_B16(a0h, b0l, acc[0][0]);
        acc[0][0] = MFMA_B16(a0l, b0h, acc[0][0]);
        acc[0][1] = MFMA_B16(a0h, b1h, acc[0][1]);
        acc[0][1] = MFMA_B16(a0h, b1l, acc[0][1]);
        acc[0][1] = MFMA_B16(a0l, b1h, acc[0][1]);
        acc[1][0] = MFMA_B16(a1h, b0h, acc[1][0]);
        acc[1][0] = MFMA_B16(a1h, b0l, acc[1][0]);
        acc[1][0] = MFMA_B16(a1l, b0h, acc[1][0]);
        acc[1][1] = MFMA_B16(a1h, b1h, acc[1][1]);
        acc[1][1] = MFMA_B16(a1h, b1l, acc[1][1]);
        acc[1][1] = MFMA_B16(a1l, b1h, acc[1][1]);
        __builtin_amdgcn_s_setprio(0);
      }
      if (!last) loadAh1(nfc);
    }
    if (si < 35) {
      BARRIER_RAW();            // all slab reads consumed
      writeSlab();              // slab si+1 (vmcnt auto-wait on rs)
      if (si + 2 < 36) issueSlab(si + 2);
      BARRIER_NODRAIN();        // publish ds_writes; keep vmem in flight
    }
    dyi = ndyi; cidx = ncidx;
  }

  // epilogue
#pragma unroll
  for (int t = 0; t < 2; ++t) {
    int mb = m0 + wm * 64 + t * 32;
#pragma unroll
    for (int s = 0; s < 2; ++s) {
      int n = n0 + wn * 64 + s * 32 + lm;
#pragma unroll
      for (int g = 0; g < 16; ++g) {
        int m = mb + (g & 3) + ((g >> 2) << 3) + (lh << 2);
        Y[((size_t)b * CCH + m) * HWN + n] = acc[t][s][g] + bias[m];
      }
    }
  }
}

// -------- FFT2 pass: stages 0+1 fused in registers, stage 2 via LDS ---------
// Each thread owns 16 consecutive elements (seg) of one line: closed under
// stage 0 (stride 1) and stage 1 (stride 4) -> both computed in registers
// with ONE LDS round trip; stage 2 (stride 16) as before.  2 barriers/pass
// instead of 3; LDS ops 32r+32w vs 48r+48w per thread per pass.
__device__ __forceinline__ void fft4_pass(float* zr, float* zi,
    const float* twr, const float* twi, int tid, int axis, float ds) {
  int line = tid >> 2, seg = tid & 3;
  int base, st;
  if (axis == 0) { base = line * FFTP + (seg << 4); st = 1; }
  else           { base = (seg << 4) * FFTP + line; st = FFTP; }
  float xr[16], xi[16];
#pragma unroll
  for (int e = 0; e < 16; ++e) { xr[e] = zr[base + e*st]; xi[e] = zi[base + e*st]; }
  // stage 0: h=1, j=0 (w1=w2=1), butterflies on {4q..4q+3}
#pragma unroll
  for (int q = 0; q < 4; ++q) {
    int i0 = q << 2;
    float u0r = xr[i0] + xr[i0+1],   u0i = xi[i0] + xi[i0+1];
    float u1r = xr[i0] - xr[i0+1],   u1i = xi[i0] - xi[i0+1];
    float u2r = xr[i0+2] + xr[i0+3], u2i = xi[i0+2] + xi[i0+3];
    float u3r = xr[i0+2] - xr[i0+3], u3i = xi[i0+2] - xi[i0+3];
    xr[i0]   = u0r + u2r;      xi[i0]   = u0i + u2i;
    xr[i0+2] = u0r - u2r;      xi[i0+2] = u0i - u2i;
    xr[i0+1] = u1r + ds*u3i;   xi[i0+1] = u1i - ds*u3r;
    xr[i0+3] = u1r - ds*u3i;   xi[i0+3] = u1i + ds*u3r;
  }
  // stage 1: h=4, local butterflies {j, j+4, j+8, j+12}, e1=j<<3, e2=j<<2
#pragma unroll
  for (int j = 0; j < 4; ++j) {
    float w1r = twr[j << 3], w1i = ds * twi[j << 3];
    float w2r = twr[j << 2], w2i = ds * twi[j << 2];
    int A0 = j, A1 = j + 4, A2 = j + 8, A3 = j + 12;
    float x1r = xr[A1], x1i = xi[A1], x3r = xr[A3], x3i = xi[A3];
    float t1r = x1r*w1r - x1i*w1i, t1i = x1r*w1i + x1i*w1r;
    float t3r = x3r*w1r - x3i*w1i, t3i = x3r*w1i + x3i*w1r;
    float u0r = xr[A0] + t1r, u0i = xi[A0] + t1i;
    float u1r = xr[A0] - t1r, u1i = xi[A0] - t1i;
    float u2r = xr[A2] + t3r, u2i = xi[A2] + t3i;
    float u3r = xr[A2] - t3r, u3i = xi[A2] - t3i;
    float c2r = u2r*w2r - u2i*w2i, c2i = u2r*w2i + u2i*w2r;
    float c3r = u3r*w2r - u3i*w2i, c3i = u3r*w2i + u3i*w2r;
    xr[A0] = u0r + c2r;      xi[A0] = u0i + c2i;
    xr[A2] = u0r - c2r;      xi[A2] = u0i - c2i;
    xr[A1] = u1r + ds*c3i;   xi[A1] = u1i - ds*c3r;
    xr[A3] = u1r - ds*c3i;   xi[A3] = u1i + ds*c3r;
  }
#pragma unroll
  for (int e = 0; e < 16; ++e) { zr[base + e*st] = xr[e]; zi[base + e*st] = xi[e]; }
  __syncthreads();
  // stage 2: h=16, butterflies {j, j+16, j+32, j+48}, e1=j<<1, e2=j
#pragma unroll
  for (int tt = 0; tt < 4; ++tt) {
    int t = tid + (tt << 8);
    int line2 = t >> 4, j = t & 15;
    float w1r = twr[j << 1], w1i = ds * twi[j << 1];
    float w2r = twr[j],      w2i = ds * twi[j];
    int A0, st2;
    if (axis == 0) { A0 = line2 * FFTP + j; st2 = 16; }
    else           { A0 = j * FFTP + line2; st2 = 16 * FFTP; }
    int A1 = A0 + st2, A2 = A1 + st2, A3 = A2 + st2;
    float x0r = zr[A0], x0i = zi[A0];
    float x1r = zr[A1], x1i = zi[A1];
    float x2r = zr[A2], x2i = zi[A2];
    float x3r = zr[A3], x3i = zi[A3];
    float t1r = x1r*w1r - x1i*w1i, t1i = x1r*w1i + x1i*w1r;
    float t3r = x3r*w1r - x3i*w1i, t3i = x3r*w1i + x3i*w1r;
    float u0r = x0r + t1r, u0i = x0i + t1i;
    float u1r = x0r - t1r, u1i = x0i - t1i;
    float u2r = x2r + t3r, u2i = x2i + t3i;
    float u3r = x2r - t3r, u3i = x2i - t3i;
    float c2r = u2r*w2r - u2i*w2i, c2i = u2r*w2i + u2i*w2r;
    float c3r = u3r*w2r - u3i*w2i, c3i = u3r*w2i + u3i*w2r;
    zr[A0] = u0r + c2r;      zi[A0] = u0i + c2i;
    zr[A2] = u0r - c2r;      zi[A2] = u0i - c2i;
    zr[A1] = u1r + ds*c3i;   zi[A1] = u1i - ds*c3r;
    zr[A3] = u1r - ds*c3i;   zi[A3] = u1i + ds*c3r;
  }
  __syncthreads();
}

// --------- fused: circ-conv(q,k) via FFT + exact top-k + softmax + *v -------
// F4 may alias q (block reads its q range fully before writing F4).
__global__ __launch_bounds__(256) void fft_topk_kernel(
    const float* q, const float* __restrict__ kkb,
    const __half* __restrict__ v, float* F4) {
  __shared__ float zr[64 * FFTP], zi[64 * FFTP];
  __shared__ float twr[32], twi[32];
  __shared__ unsigned hist[4][256];        // per-wave sub-histograms
  __shared__ unsigned su2[2];
  __shared__ unsigned wtot[4];
  __shared__ float sred[5];
  int tid = threadIdx.x;
  int lane = tid & 63, w = tid >> 6;
  size_t base = (size_t)blockIdx.x * HWN;
  for (int i = tid; i < HWN; i += 256) {
    int y = i >> 6, x = i & 63;
    int slot = br6(y) * FFTP + br6(x);
    zr[slot] = q[base + i];
    zi[slot] = kkb[base + i];
  }
  if (tid < 32) {
    float ang = (float)tid * 0.0981747704246810387f;  // 2*pi/64
    twr[tid] = cosf(ang);
    twi[tid] = -sinf(ang);                            // forward e^{-i theta}
  }
  __syncthreads();
  fft4_pass(zr, zi, twr, twi, tid, 0, 1.f);
  fft4_pass(zr, zi, twr, twi, tid, 1, 1.f);
  // split Z into Fq,Fk via Hermitian symmetry; P = Fq*Fk
  float prr[16], pir[16];
#pragma unroll
  for (int c = 0; c < 16; c++) {
    int i = tid + (c << 8);
    int ky = i >> 6, kx = i & 63;
    float sr = zr[ky * FFTP + kx], si = zi[ky * FFTP + kx];
    int kyn = (64 - ky) & 63, kxn = (64 - kx) & 63;
    float nr = zr[kyn * FFTP + kxn], ni = zi[kyn * FFTP + kxn];
    float fqr = 0.5f * (sr + nr), fqi = 0.5f * (si - ni);
    float fkr = 0.5f * (si + ni), fki = 0.5f * (nr - sr);
    prr[c] = fqr * fkr - fqi * fki;
    pir[c] = fqr * fki + fqi * fkr;
  }
  __syncthreads();
#pragma unroll
  for (int c = 0; c < 16; c++) {
    int i = tid + (c << 8);
    int ky = i >> 6, kx = i & 63;
    int slot = br6(ky) * FFTP + br6(kx);
    zr[slot] = prr[c];
    zi[slot] = pir[c];
  }
  __syncthreads();
  fft4_pass(zr, zi, twr, twi, tid, 0, -1.f);
  fft4_pass(zr, zi, twr, twi, tid, 1, -1.f);
  // pull this thread's 16 A values into registers; LDS not re-read after this
  const float scale = 1.0f / 4096.0f;
  float a[16];
  unsigned key[16];
  float mx = -3.0e38f;
#pragma unroll
  for (int c = 0; c < 16; c++) {
    int i = tid + (c << 8);
    a[c] = zr[(i >> 6) * FFTP + (i & 63)] * scale;
    key[c] = f2key(a[c]);
    mx = fmaxf(mx, a[c]);
  }
  mx = wave_max(mx);
  if (lane == 0) sred[w] = mx;
  __syncthreads();
  if (tid == 0) sred[4] = fmaxf(fmaxf(sred[0], sred[1]), fmaxf(sred[2], sred[3]));
  __syncthreads();
  float am = sred[4];
  // 4-pass byte radix select (exact 512th-largest key), shuffle-based scan
  unsigned prefix = 0; int kr = KSEL;
  for (int pass = 0; pass < 4; pass++) {
    int shift = 24 - (pass << 3);
#pragma unroll
    for (int ww = 0; ww < 4; ++ww) hist[ww][tid] = 0;
    __syncthreads();
#pragma unroll
    for (int c = 0; c < 16; c++) {
      unsigned u = key[c];
      if (((u ^ prefix) >> shift) <= 0xFFu)
        atomicAdd(&hist[w][(u >> shift) & 255u], 1u);
    }
    __syncthreads();
    unsigned xv = hist[0][tid] + hist[1][tid] + hist[2][tid] + hist[3][tid];
#pragma unroll
    for (int o = 1; o < 64; o <<= 1) {      // intra-wave suffix scan
      unsigned t2 = __shfl_down(xv, o, 64);
      if (lane + o < 64) xv += t2;
    }
    if (lane == 0) wtot[w] = xv;
    __syncthreads();
    for (int ww = w + 1; ww < 4; ++ww) xv += wtot[ww];
    hist[0][tid] = xv;                       // S[t] = #keys with byte >= t
    __syncthreads();
    unsigned sv = xv;
    unsigned svn = (tid < 255) ? hist[0][tid + 1] : 0u;
    if (sv >= (unsigned)kr && svn < (unsigned)kr) { su2[0] = (unsigned)tid; su2[1] = svn; }
    __syncthreads();
    prefix |= su2[0] << shift;
    kr -= (int)su2[1];
  }
  unsigned thr = prefix;
  float lsum = 0.f;
#pragma unroll
  for (int c = 0; c < 16; c++)
    if (key[c] >= thr) lsum += expf(a[c] - am);
  lsum = wave_sum(lsum);
  if (lane == 0) sred[w] = lsum;
  __syncthreads();
  if (tid == 0) sred[4] = 1.0f / (sred[0] + sred[1] + sred[2] + sred[3]);
  __syncthreads();
  float inv = sred[4];
#pragma unroll
  for (int c = 0; c < 16; c++) {
    int i = tid + (c << 8);
    float wgt = (key[c] >= thr) ? expf(a[c] - am) * inv : 0.f;
    F4[base + i] = __half2float(v[base + i]) * wgt;
  }
}

extern "C" void kernel_launch(void* const* d_in, const int* in_sizes, int n_in,
                              void* d_out, int out_size, void* d_ws, size_t ws_size,
                              hipStream_t stream) {
  const float* x     = (const float*)d_in[0];
  const float* gamma = (const float*)d_in[1];
  const float* beta  = (const float*)d_in[2];
  const float* wq    = (const float*)d_in[3];
  const float* bq    = (const float*)d_in[4];
  const float* wk    = (const float*)d_in[5];
  const float* bk    = (const float*)d_in[6];
  const float* wv    = (const float*)d_in[7];
  const float* bv    = (const float*)d_in[8];
  const float* wf    = (const float*)d_in[9];
  const float* bf    = (const float*)d_in[10];

  const size_t NEL = (size_t)BATCH * CCH * HWN;   // 12,582,912
  const size_t WSZ = (size_t)CCH * CCH;           // 147,456

  unsigned short* xnTh = (unsigned short*)d_ws;        // bf16 NHWC hi
  unsigned short* xnTl = xnTh + NEL;                   // bf16 NHWC lo
  float*  qC  = (float*)(xnTl + NEL);                  // q fp32 -> F4 fp32
  float*  kD  = qC + NEL;                              // k fp32 -> F4T hi/lo
  __half* vE  = (__half*)(kD + NEL);                   // v fp16
  unsigned short* W = (unsigned short*)(vE + NEL);
  unsigned short* Wqh = W;
  unsigned short* Wql = Wqh + WSZ;
  unsigned short* Wvh = Wql + WSZ;
  unsigned short* Wvl = Wvh + WSZ;
  unsigned short* Wfh = Wvl + WSZ;
  unsigned short* Wfl = Wfh + WSZ;
  unsigned short* Wkh = Wfl + WSZ;                     // 9*147456
  unsigned short* Wkl = Wkh + 9 * WSZ;
  float2* gs = (float2*)(Wkl + 9 * WSZ);
  unsigned short* zp = (unsigned short*)(gs + BATCH * NG);  // 16B zero page
  unsigned short* F4Th = (unsigned short*)kD;          // reuse k region
  unsigned short* F4Tl = F4Th + NEL;

  pack_split_k<<<dim3(576), dim3(256), 0, stream>>>(wq, Wqh, Wql, (int)WSZ);
  pack_split_k<<<dim3(576), dim3(256), 0, stream>>>(wv, Wvh, Wvl, (int)WSZ);
  pack_split_k<<<dim3(576), dim3(256), 0, stream>>>(wf, Wfh, Wfl, (int)WSZ);
  pack9_k<<<dim3(576, 9), dim3(256), 0, stream>>>(wk, Wkh, Wkl);
  stats_kernel<<<dim3(BATCH * NG), dim3(256), 0, stream>>>(x, gs, zp);
  trans_kernel<1, 1><<<dim3(64, 6, BATCH), dim3(256), 0, stream>>>(
      x, gs, gamma, beta, xnTh, xnTl);

  dim3 gm(32, 3, BATCH);
  mm_kernel<1, 0><<<gm, dim3(256), 0, stream>>>(Wqh, Wql, bq, xnTh, xnTl,
                                                nullptr, nullptr, qC);
  mm9_kernel<<<gm, dim3(256), 0, stream>>>(Wkh, Wkl, bk, xnTh, xnTl, zp, kD);
  mm_kernel<1, 1><<<gm, dim3(256), 0, stream>>>(Wvh, Wvl, bv, xnTh, xnTl,
                                                nullptr, nullptr, vE);

  fft_topk_kernel<<<dim3(BATCH * CCH), dim3(256), 0, stream>>>(qC, kD, vE, qC);

  trans_kernel<0, 1><<<dim3(64, 6, BATCH), dim3(256), 0, stream>>>(
      qC, nullptr, nullptr, nullptr, F4Th, F4Tl);

  mm_kernel<1, 2><<<gm, dim3(256), 0, stream>>>(Wfh, Wfl, bf, F4Th, F4Tl,
                                                xnTh, xnTl, d_out);
}